// Round 1
// baseline (1164.397 us; speedup 1.0000x reference)
//
#include <hip/hip_runtime.h>

// FusedLoRA: x[4,4096,4096] f32; 3x (A[4096,8], B[8,4096]) f32
// out[4,4096,3*4096] = concat_l( (x @ A_l) @ B_l * scale ), scale = 1.0
//
// Phase 1: xa[16384][24] = x @ [A0|A1|A2]   (read-bound: 268 MB x)
// Phase 2: out[row][l*4096+o] = sum_r xa[row][l*8+r] * B_l[r][o]  (write-bound: 805 MB)

#define DIM       4096
#define M_ROWS    16384          // 4 * 4096
#define NLORA     3
#define RANK      8
#define NC        24             // NLORA * RANK
#define OUT_COLS  12288          // NLORA * DIM

// ---------------- Phase 1 ----------------
#define KC             512       // K-chunk staged in LDS (At = 24*512*4 = 48 KB)
#define ROWS_PER_WAVE  4
#define ROWS_PER_BLOCK 16        // 4 waves * 4 rows

__launch_bounds__(256, 2)
__global__ void lora_xa_kernel(const float* __restrict__ x,
                               const float* __restrict__ A0,
                               const float* __restrict__ A1,
                               const float* __restrict__ A2,
                               float* __restrict__ xa) {
  // Transposed layout: At[c][k_local]. For the compute read (fixed c, lane-varying k)
  // lane addresses are consecutive 16 B -> conflict-free ds_read_b128.
  __shared__ float At[NC][KC];

  const int tid  = threadIdx.x;
  const int lane = tid & 63;
  const int wave = tid >> 6;
  const int row0 = blockIdx.x * ROWS_PER_BLOCK + wave * ROWS_PER_WAVE;

  float acc[ROWS_PER_WAVE][NC];
#pragma unroll
  for (int r = 0; r < ROWS_PER_WAVE; ++r)
#pragma unroll
    for (int c = 0; c < NC; ++c) acc[r][c] = 0.f;

  for (int kb = 0; kb < DIM; kb += KC) {
    // ---- stage A chunk (transposed) into LDS ----
    // per lora: KC*8 floats = KC*2 float4; 3 loras = 12 float4 per thread (256 thr)
#pragma unroll
    for (int j = 0; j < 12; ++j) {
      const int l   = j >> 2;                   // compile-time after unroll
      const int rem = tid + (j & 3) * 256;      // float4 index within lora chunk
      const int dof = rem >> 1;                 // d offset in chunk
      const int rq  = (rem & 1) * 4;            // r quad: 0 or 4
      const float* Ap = (l == 0) ? A0 : (l == 1) ? A1 : A2;
      const float4 v = *(const float4*)(Ap + (size_t)(kb + dof) * RANK + rq);
      At[l * RANK + rq + 0][dof] = v.x;
      At[l * RANK + rq + 1][dof] = v.y;
      At[l * RANK + rq + 2][dof] = v.z;
      At[l * RANK + rq + 3][dof] = v.w;
    }
    __syncthreads();

#pragma unroll
    for (int step = 0; step < KC / 256; ++step) {
      const int kl = step * 256 + 4 * lane;     // local k quad for this lane
      const int kq = kb + kl;                   // global k
      float4 xv[ROWS_PER_WAVE];
#pragma unroll
      for (int r = 0; r < ROWS_PER_WAVE; ++r)
        xv[r] = *(const float4*)(x + (size_t)(row0 + r) * DIM + kq);
#pragma unroll
      for (int c = 0; c < NC; ++c) {
        const float4 av = *(const float4*)(&At[c][kl]);
#pragma unroll
        for (int r = 0; r < ROWS_PER_WAVE; ++r) {
          acc[r][c] = fmaf(xv[r].x, av.x, acc[r][c]);
          acc[r][c] = fmaf(xv[r].y, av.y, acc[r][c]);
          acc[r][c] = fmaf(xv[r].z, av.z, acc[r][c]);
          acc[r][c] = fmaf(xv[r].w, av.w, acc[r][c]);
        }
      }
    }
    __syncthreads();
  }

  // ---- 64-lane butterfly reduction (once per row: ~4 us globally) ----
#pragma unroll
  for (int r = 0; r < ROWS_PER_WAVE; ++r)
#pragma unroll
    for (int c = 0; c < NC; ++c) {
      float v = acc[r][c];
#pragma unroll
      for (int off = 32; off > 0; off >>= 1) v += __shfl_xor(v, off, 64);
      acc[r][c] = v;
    }

  // lane c takes column c (compile-time register index, runtime lane predicate)
  float outv[ROWS_PER_WAVE];
#pragma unroll
  for (int c = 0; c < NC; ++c)
#pragma unroll
    for (int r = 0; r < ROWS_PER_WAVE; ++r)
      if (lane == c) outv[r] = acc[r][c];

  if (lane < NC) {
#pragma unroll
    for (int r = 0; r < ROWS_PER_WAVE; ++r)
      xa[(size_t)(row0 + r) * NC + lane] = outv[r];
  }
}

// ---------------- Phase 2 ----------------
#define ROW_TILE        128
#define COLS_PER_BLOCK  1024     // 256 threads * float4

__launch_bounds__(256, 4)
__global__ void lora_expand_kernel(const float* __restrict__ xa,
                                   const float* __restrict__ B0,
                                   const float* __restrict__ B1,
                                   const float* __restrict__ B2,
                                   float* __restrict__ out) {
  // grid: (OUT_COLS / COLS_PER_BLOCK) x (M_ROWS / ROW_TILE) = 12 x 128
  const int ctile = blockIdx.x;                 // 0..11
  const int rtile = blockIdx.y;                 // 0..127
  const int l     = ctile >> 2;                 // 4 col tiles per lora
  const int o     = (ctile & 3) * COLS_PER_BLOCK + threadIdx.x * 4; // within lora
  const float* B  = (l == 0) ? B0 : (l == 1) ? B1 : B2;

  // B fragment lives in registers for the whole row loop (32 VGPRs)
  float4 b[RANK];
#pragma unroll
  for (int r = 0; r < RANK; ++r)
    b[r] = *(const float4*)(B + (size_t)r * DIM + o);

  const int row0    = rtile * ROW_TILE;
  const size_t ocol = (size_t)l * DIM + o;

  for (int i = 0; i < ROW_TILE; ++i) {
    const int row = row0 + i;
    const float* xr = xa + (size_t)row * NC + l * RANK;  // 16B-aligned
    const float4 s0 = *(const float4*)(xr);      // wave-uniform -> L1 broadcast
    const float4 s1 = *(const float4*)(xr + 4);
    const float s[8] = {s0.x, s0.y, s0.z, s0.w, s1.x, s1.y, s1.z, s1.w};

    float4 acc = {0.f, 0.f, 0.f, 0.f};
#pragma unroll
    for (int r = 0; r < RANK; ++r) {
      acc.x = fmaf(s[r], b[r].x, acc.x);
      acc.y = fmaf(s[r], b[r].y, acc.y);
      acc.z = fmaf(s[r], b[r].z, acc.z);
      acc.w = fmaf(s[r], b[r].w, acc.w);
    }
    *(float4*)(out + (size_t)row * OUT_COLS + ocol) = acc;
  }
}

extern "C" void kernel_launch(void* const* d_in, const int* in_sizes, int n_in,
                              void* d_out, int out_size, void* d_ws, size_t ws_size,
                              hipStream_t stream) {
  const float* x  = (const float*)d_in[0];
  const float* A0 = (const float*)d_in[1];
  const float* B0 = (const float*)d_in[2];
  const float* A1 = (const float*)d_in[3];
  const float* B1 = (const float*)d_in[4];
  const float* A2 = (const float*)d_in[5];
  const float* B2 = (const float*)d_in[6];
  float* out = (float*)d_out;
  float* xa  = (float*)d_ws;                    // 16384*24*4 = 1.5 MB

  if (ws_size < (size_t)M_ROWS * NC * sizeof(float)) return;  // scratch too small

  lora_xa_kernel<<<dim3(M_ROWS / ROWS_PER_BLOCK), dim3(256), 0, stream>>>(
      x, A0, A1, A2, xa);
  lora_expand_kernel<<<dim3(OUT_COLS / COLS_PER_BLOCK, M_ROWS / ROW_TILE),
                       dim3(256), 0, stream>>>(xa, B0, B1, B2, out);
}